// Round 8
// baseline (72987.311 us; speedup 1.0000x reference)
//
#include <hip/hip_runtime.h>

#define NWG   256
#define TPB_R 512     // persistent-register kernel: 8 waves, 2/SIMD, 256-VGPR budget
#define TPB_S 1024    // fallback streaming kernel
#define NSTEP 1000
#define NDATA 2048
#define WIDTH 4096

typedef __attribute__((ext_vector_type(4))) float f32x4;
typedef __attribute__((ext_vector_type(2))) float f32x2;
typedef __attribute__((ext_vector_type(2))) unsigned int u32x2;
typedef __attribute__((ext_vector_type(4))) unsigned int u32x4;
typedef unsigned int uint;

#define SCHED_FENCE() __builtin_amdgcn_sched_barrier(0)

// ---------- scalar helpers ----------

__device__ __forceinline__ float sp_f(float v) {
  // jax.nn.softplus == max(v,0) + log1p(exp(-|v|))
  return fmaxf(v, 0.0f) + log1pf(expf(-fabsf(v)));
}

__device__ __forceinline__ float wred(float v) {
#pragma unroll
  for (int m = 32; m > 0; m >>= 1) v += __shfl_xor(v, m, 64);
  return v;
}

// ---------- waits / barriers ----------

__device__ __forceinline__ void wait_vm0()   { asm volatile("s_waitcnt vmcnt(0)" ::: "memory"); SCHED_FENCE(); }
template<int N>
__device__ __forceinline__ void wait_vmN()   { asm volatile("s_waitcnt vmcnt(%0)" :: "n"(N) : "memory"); SCHED_FENCE(); }
__device__ __forceinline__ void wait_lgkm0() { asm volatile("s_waitcnt lgkmcnt(0)" ::: "memory"); SCHED_FENCE(); }
__device__ __forceinline__ void wgbar()      { __builtin_amdgcn_s_barrier(); SCHED_FENCE(); }

// ---------- L2-bypass (coherent) activation I/O ----------

__device__ __forceinline__ void st_sc_x1(float* p, float v) {
  asm volatile("global_store_dword %0, %1, off sc0 sc1" :: "v"(p), "v"(v) : "memory");
}
__device__ __forceinline__ void st_sc_x2(float* p, f32x2 v) {
  asm volatile("global_store_dwordx2 %0, %1, off sc0 sc1" :: "v"(p), "v"(v) : "memory");
}
__device__ __forceinline__ void ld_sc_x1_issue(const float* p, float& v) {
  asm volatile("global_load_dword %0, %1, off sc0 sc1" : "=v"(v) : "v"(p) : "memory");
}
__device__ __forceinline__ void ld_sc_x4_issue(const f32x4* p, f32x4& v) {
  asm volatile("global_load_dwordx4 %0, %1, off sc0 sc1" : "=v"(v) : "v"(p) : "memory");
}

// ---------- activation staging into LDS (bypass loads) ----------

__device__ __forceinline__ void stage4096_512(const float* src, float* xs, int tid) {
  f32x4 a, b;
  ld_sc_x4_issue((const f32x4*)src + tid, a);
  ld_sc_x4_issue((const f32x4*)src + tid + 512, b);
  wait_vm0();
  ((f32x4*)xs)[tid] = a;
  ((f32x4*)xs)[tid + 512] = b;
  wait_lgkm0();
  wgbar();
}
__device__ __forceinline__ void stage2048_512(const float* src, float* xs, int tid) {
  f32x4 a;
  ld_sc_x4_issue((const f32x4*)src + tid, a);
  wait_vm0();
  ((f32x4*)xs)[tid] = a;
  wait_lgkm0();
  wgbar();
}

// ---------- fence-free grid barrier (monotonic 2-level counter tree) ----------

__device__ __forceinline__ void gbar(unsigned* gcnt, unsigned* root,
                                     unsigned b, int wg, int tid) {
  wgbar();
  if (tid == 0) {
    unsigned old = __hip_atomic_fetch_add(&gcnt[(wg >> 4) * 16], 1u,
                                          __ATOMIC_RELAXED, __HIP_MEMORY_SCOPE_AGENT);
    if ((old & 15u) == 15u)
      __hip_atomic_fetch_add(root, 1u, __ATOMIC_RELAXED, __HIP_MEMORY_SCOPE_AGENT);
    const unsigned target = 16u * (b + 1u);
    while (__hip_atomic_load(root, __ATOMIC_RELAXED, __HIP_MEMORY_SCOPE_AGENT) < target)
      __builtin_amdgcn_s_sleep(1);
  }
  wgbar();
}

// ---------- fp32 -> bf16 (RNE) weight conversion ----------

__device__ __forceinline__ uint bfr(float f) {
  uint u = __float_as_uint(f);
  return (u + 0x7fffu + ((u >> 16) & 1u)) >> 16;
}

__global__ void cvt_bf16(const float* __restrict__ in, uint* __restrict__ out, int n4) {
  int i = blockIdx.x * 256 + threadIdx.x;
  if (i >= n4) return;
  f32x4 v = ((const f32x4*)in)[i];
  u32x2 o;
  o.x = bfr(v.x) | (bfr(v.y) << 16);
  o.y = bfr(v.z) | (bfr(v.w) << 16);
  ((u32x2*)out)[i] = o;
}

// ---------- macro-expanded bf16 dot kernels (NO arrays, named SSA only) ----
// u32x4 Q at index i*64+lane of a row covers x[512i + 8*lane .. +8):
//   Q.x -> (xv0.x, xv0.y), Q.y -> (xv0.z, xv0.w),
//   Q.z -> (xv1.x, xv1.y), Q.w -> (xv1.z, xv1.w)

#define QFMA(Q, x0, x1, s) do{                                    \
  s = fmaf(__uint_as_float((Q).x << 16),          (x0).x, s);     \
  s = fmaf(__uint_as_float((Q).x & 0xffff0000u),  (x0).y, s);     \
  s = fmaf(__uint_as_float((Q).y << 16),          (x0).z, s);     \
  s = fmaf(__uint_as_float((Q).y & 0xffff0000u),  (x0).w, s);     \
  s = fmaf(__uint_as_float((Q).z << 16),          (x1).x, s);     \
  s = fmaf(__uint_as_float((Q).z & 0xffff0000u),  (x1).y, s);     \
  s = fmaf(__uint_as_float((Q).w << 16),          (x1).z, s);     \
  s = fmaf(__uint_as_float((Q).w & 0xffff0000u),  (x1).w, s);     \
}while(0)

#define PAIR(i, Qa, Qb) do{                                       \
  f32x4 xv0 = x4[(i)*128 + 2*lane];                               \
  f32x4 xv1 = x4[(i)*128 + 2*lane + 1];                           \
  QFMA(Qa, xv0, xv1, s0); QFMA(Qb, xv0, xv1, s1);                 \
}while(0)

#define SING(i, Q) do{                                            \
  f32x4 xv0 = x4[(i)*128 + 2*lane];                               \
  f32x4 xv1 = x4[(i)*128 + 2*lane + 1];                           \
  QFMA(Q, xv0, xv1, s0);                                          \
}while(0)

// ======================================================================
// PERSISTENT-REGISTER kernel: entire bf16 weight set in 48 NAMED u32x4
// variables (192 VGPR/thread). amdgpu_waves_per_eu(2,2) pins the 256-VGPR
// budget (rounds 6/7: arrays + 128-VGPR cap -> wholesale scratch spill,
// FETCH 50 GB/step). 256 VGPR also hardware-enforces 1 WG/CU.
// ======================================================================

__global__ __attribute__((amdgpu_flat_work_group_size(TPB_R, TPB_R),
                          amdgpu_waves_per_eu(2, 2)))
void ode_reg(
    const float* __restrict__ ts, const float* __restrict__ y0,
    const uint* __restrict__ W0b, const float* __restrict__ b0,
    const uint* __restrict__ W1b, const float* __restrict__ b1,
    const uint* __restrict__ W2b, const float* __restrict__ b2,
    const uint* __restrict__ W3b, const float* __restrict__ b3,
    float* __restrict__ out, float* hA, float* hB,
    unsigned* gcnt, unsigned* root)
{
  __shared__ float xs[WIDTH];
  const int wg = blockIdx.x, tid = threadIdx.x;
  const int wave = tid >> 6, lane = tid & 63;
  const float dt = ts[1] - ts[0];
  const int rw = wg * 16 + wave * 2;   // wide layers: rows rw, rw+1
  const int rF = wg * 8 + wave;        // final layer: 1 row/wave
  const f32x4* x4 = (const f32x4*)xs;

  // ---- prologue: 48 named u32x4 weight slices (192 VGPRs) ----
  const u32x4* p0a = (const u32x4*)W0b + (size_t)rw * 256;        // K=2048: 256 u32x4/row
  const u32x4* p0b = p0a + 256;
  const u32x4* p1a = (const u32x4*)W1b + (size_t)rw * 512;        // K=4096: 512 u32x4/row
  const u32x4* p1b = p1a + 512;
  const u32x4* p2a = (const u32x4*)W2b + (size_t)rw * 512;
  const u32x4* p2b = p2a + 512;
  const u32x4* pD  = (const u32x4*)W3b + (size_t)rF * 512;

  u32x4 A00 = p0a[0*64+lane], A01 = p0a[1*64+lane], A02 = p0a[2*64+lane], A03 = p0a[3*64+lane];
  u32x4 A10 = p0b[0*64+lane], A11 = p0b[1*64+lane], A12 = p0b[2*64+lane], A13 = p0b[3*64+lane];
  u32x4 B00 = p1a[0*64+lane], B01 = p1a[1*64+lane], B02 = p1a[2*64+lane], B03 = p1a[3*64+lane];
  u32x4 B04 = p1a[4*64+lane], B05 = p1a[5*64+lane], B06 = p1a[6*64+lane], B07 = p1a[7*64+lane];
  u32x4 B10 = p1b[0*64+lane], B11 = p1b[1*64+lane], B12 = p1b[2*64+lane], B13 = p1b[3*64+lane];
  u32x4 B14 = p1b[4*64+lane], B15 = p1b[5*64+lane], B16 = p1b[6*64+lane], B17 = p1b[7*64+lane];
  u32x4 C00 = p2a[0*64+lane], C01 = p2a[1*64+lane], C02 = p2a[2*64+lane], C03 = p2a[3*64+lane];
  u32x4 C04 = p2a[4*64+lane], C05 = p2a[5*64+lane], C06 = p2a[6*64+lane], C07 = p2a[7*64+lane];
  u32x4 C10 = p2b[0*64+lane], C11 = p2b[1*64+lane], C12 = p2b[2*64+lane], C13 = p2b[3*64+lane];
  u32x4 C14 = p2b[4*64+lane], C15 = p2b[5*64+lane], C16 = p2b[6*64+lane], C17 = p2b[7*64+lane];
  u32x4 D0  = pD[0*64+lane],  D1  = pD[1*64+lane],  D2  = pD[2*64+lane],  D3  = pD[3*64+lane];
  u32x4 D4  = pD[4*64+lane],  D5  = pD[5*64+lane],  D6  = pD[6*64+lane],  D7  = pD[7*64+lane];

  const float bb0x = b0[rw], bb0y = b0[rw + 1];
  const float bb1x = b1[rw], bb1y = b1[rw + 1];
  const float bb2x = b2[rw], bb2y = b2[rw + 1];
  const float bf3  = b3[rF];

  unsigned b = 0;
  const float* yin = y0;
  for (int step = 0; step < NSTEP; ++step) {
    float s0, s1;
    // ---- L0: 2048 -> 4096, softplus ----
    stage2048_512(yin, xs, tid);
    s0 = 0.f; s1 = 0.f;
    PAIR(0, A00, A10); PAIR(1, A01, A11); PAIR(2, A02, A12); PAIR(3, A03, A13);
    s0 = wred(s0); s1 = wred(s1);
    if (lane == 0) { f32x2 v; v.x = sp_f(s0 + bb0x); v.y = sp_f(s1 + bb0y); st_sc_x2(hA + rw, v); }
    wait_vm0();
    gbar(gcnt, root, b++, wg, tid);

    // ---- L1: 4096 -> 4096, softplus ----
    stage4096_512(hA, xs, tid);
    s0 = 0.f; s1 = 0.f;
    PAIR(0, B00, B10); PAIR(1, B01, B11); PAIR(2, B02, B12); PAIR(3, B03, B13);
    PAIR(4, B04, B14); PAIR(5, B05, B15); PAIR(6, B06, B16); PAIR(7, B07, B17);
    s0 = wred(s0); s1 = wred(s1);
    if (lane == 0) { f32x2 v; v.x = sp_f(s0 + bb1x); v.y = sp_f(s1 + bb1y); st_sc_x2(hB + rw, v); }
    wait_vm0();
    gbar(gcnt, root, b++, wg, tid);

    // ---- L2: 4096 -> 4096, softplus ----
    stage4096_512(hB, xs, tid);
    s0 = 0.f; s1 = 0.f;
    PAIR(0, C00, C10); PAIR(1, C01, C11); PAIR(2, C02, C12); PAIR(3, C03, C13);
    PAIR(4, C04, C14); PAIR(5, C05, C15); PAIR(6, C06, C16); PAIR(7, C07, C17);
    s0 = wred(s0); s1 = wred(s1);
    if (lane == 0) { f32x2 v; v.x = sp_f(s0 + bb2x); v.y = sp_f(s1 + bb2y); st_sc_x2(hA + rw, v); }
    wait_vm0();
    gbar(gcnt, root, b++, wg, tid);

    // ---- LF: 4096 -> 2048, y += dt*(W3 h + b3) ----
    stage4096_512(hA, xs, tid);
    float yo;
    ld_sc_x1_issue(yin + rF, yo);          // in flight during the dot
    s0 = 0.f;
    SING(0, D0); SING(1, D1); SING(2, D2); SING(3, D3);
    SING(4, D4); SING(5, D5); SING(6, D6); SING(7, D7);
    s0 = wred(s0);
    wait_vm0();                            // yo ready
    float* yout = out + (size_t)step * NDATA;
    if (lane == 0) st_sc_x1(yout + rF, yo + dt * (s0 + bf3));
    wait_vm0();                            // drain y store before arrival
    gbar(gcnt, root, b++, wg, tid);
    yin = yout;                            // y state lives in d_out rows
  }
}

// ======================================================================
// FALLBACK (ws too small for bf16 buffers): round-5 fp32 streaming kernel.
// ======================================================================

__device__ __forceinline__ void issue_row_f32(const float* W, size_t elemidx, int lane, f32x4* wr, int ni) {
  const f32x4* p = (const f32x4*)(W + elemidx) + lane;
  for (int i = 0; i < ni; ++i)
    asm volatile("global_load_dwordx4 %0, %1, off" : "=v"(wr[i]) : "v"(p + i * 64) : "memory");
}

template<int NI>
__device__ __forceinline__ float dot_row_f32(const f32x4* wr, const float* xs, int xoff, int lane) {
  const f32x4* x4 = (const f32x4*)xs + xoff;
  float a = 0.f;
#pragma unroll
  for (int i = 0; i < NI; ++i) {
    f32x4 xv = x4[i * 64 + lane];
    a = fmaf(wr[i].x, xv.x, a); a = fmaf(wr[i].y, xv.y, a);
    a = fmaf(wr[i].z, xv.z, a); a = fmaf(wr[i].w, xv.w, a);
  }
  return a;
}

__device__ __forceinline__ void stage4096_1024(const float* src, float* xs, int tid) {
  f32x4 a;
  ld_sc_x4_issue((const f32x4*)src + tid, a);
  wait_vm0();
  ((f32x4*)xs)[tid] = a;
  wait_lgkm0();
  wgbar();
}
__device__ __forceinline__ void stage2048_1024(const float* src, float* xs, int tid) {
  f32x4 a;
  bool act = tid < 512;
  if (act) ld_sc_x4_issue((const f32x4*)src + tid, a);
  wait_vm0();
  if (act) ((f32x4*)xs)[tid] = a;
  wait_lgkm0();
  wgbar();
}

__global__ void __launch_bounds__(TPB_S, 1) ode_stream(
    const float* __restrict__ ts, const float* __restrict__ y0,
    const float* __restrict__ W0, const float* __restrict__ b0,
    const float* __restrict__ W1, const float* __restrict__ b1,
    const float* __restrict__ W2, const float* __restrict__ b2,
    const float* __restrict__ W3, const float* __restrict__ b3,
    float* __restrict__ out, float* hA, float* hB,
    unsigned* gcnt, unsigned* root)
{
  __shared__ float xs[WIDTH];
  __shared__ float ps[16];
  const int wg = blockIdx.x, tid = threadIdx.x;
  const int wave = tid >> 6, lane = tid & 63;
  const float dt = ts[1] - ts[0];
  const int rw = wg * 16 + wave;
  const int rF = wg * 8 + (wave >> 1);
  const int hf = wave & 1;

  f32x4 w0r[8], w1r[16], w2r[16], w3r[8];
  issue_row_f32(W0, (size_t)rw * NDATA, lane, w0r, 8);

  unsigned b = 0;
  const float* yin = y0;
  for (int step = 0; step < NSTEP; ++step) {
    stage2048_1024(yin, xs, tid);
    float a = wred(dot_row_f32<8>(w0r, xs, 0, lane));
    if (lane == 0) st_sc_x1(hA + rw, sp_f(a + b0[rw]));
    issue_row_f32(W1, (size_t)rw * WIDTH, lane, w1r, 16);
    wait_vmN<16>();
    gbar(gcnt, root, b++, wg, tid);

    stage4096_1024(hA, xs, tid);
    a = wred(dot_row_f32<16>(w1r, xs, 0, lane));
    if (lane == 0) st_sc_x1(hB + rw, sp_f(a + b1[rw]));
    issue_row_f32(W2, (size_t)rw * WIDTH, lane, w2r, 16);
    wait_vmN<16>();
    gbar(gcnt, root, b++, wg, tid);

    stage4096_1024(hB, xs, tid);
    a = wred(dot_row_f32<16>(w2r, xs, 0, lane));
    if (lane == 0) st_sc_x1(hA + rw, sp_f(a + b2[rw]));
    issue_row_f32(W3, (size_t)rF * WIDTH + (size_t)hf * 2048, lane, w3r, 8);
    wait_vmN<8>();
    gbar(gcnt, root, b++, wg, tid);

    stage4096_1024(hA, xs, tid);
    float yo;
    ld_sc_x1_issue(yin + rF, yo);
    a = wred(dot_row_f32<8>(w3r, xs, hf * 512, lane));
    if (lane == 0) ps[wave] = a;
    wait_lgkm0();
    wgbar();
    wait_vm0();
    float* yout = out + (size_t)step * NDATA;
    if (hf == 0 && lane == 0) {
      float tot = ps[wave] + ps[wave + 1];
      st_sc_x1(yout + rF, yo + dt * (tot + b3[rF]));
    }
    issue_row_f32(W0, (size_t)rw * NDATA, lane, w0r, 8);
    wait_vmN<8>();
    gbar(gcnt, root, b++, wg, tid);
    yin = yout;
  }
}

// ---------- launch ----------

#define WS_HA   0
#define WS_HB   16384
#define WS_CNT  32768
#define WS_WB   65536
static const size_t N_W0 = (size_t)WIDTH * NDATA;   // 8.39M
static const size_t N_W1 = (size_t)WIDTH * WIDTH;   // 16.78M
static const size_t N_W3 = (size_t)NDATA * WIDTH;   // 8.39M

extern "C" void kernel_launch(void* const* d_in, const int* in_sizes, int n_in,
                              void* d_out, int out_size, void* d_ws, size_t ws_size,
                              hipStream_t stream) {
  const float* ts = (const float*)d_in[0];
  const float* y0 = (const float*)d_in[1];
  const float* W0 = (const float*)d_in[2];
  const float* b0 = (const float*)d_in[3];
  const float* W1 = (const float*)d_in[4];
  const float* b1 = (const float*)d_in[5];
  const float* W2 = (const float*)d_in[6];
  const float* b2 = (const float*)d_in[7];
  const float* W3 = (const float*)d_in[8];
  const float* b3 = (const float*)d_in[9];
  float* out = (float*)d_out;

  char* ws = (char*)d_ws;
  float*    hA   = (float*)(ws + WS_HA);
  float*    hB   = (float*)(ws + WS_HB);
  unsigned* gcnt = (unsigned*)(ws + WS_CNT);
  unsigned* root = (unsigned*)(ws + WS_CNT + 1024);

  hipMemsetAsync(ws + WS_CNT, 0, 4096, stream);

  const size_t need = WS_WB + (N_W0 + 2 * N_W1 + N_W3) * 2;  // ~100.7 MB
  if (ws_size >= need) {
    uint* W0b = (uint*)(ws + WS_WB);
    uint* W1b = W0b + N_W0 / 2;
    uint* W2b = W1b + N_W1 / 2;
    uint* W3b = W2b + N_W1 / 2;
    hipLaunchKernelGGL(cvt_bf16, dim3((unsigned)(N_W0 / 4 / 256)), dim3(256), 0, stream, W0, W0b, (int)(N_W0 / 4));
    hipLaunchKernelGGL(cvt_bf16, dim3((unsigned)(N_W1 / 4 / 256)), dim3(256), 0, stream, W1, W1b, (int)(N_W1 / 4));
    hipLaunchKernelGGL(cvt_bf16, dim3((unsigned)(N_W1 / 4 / 256)), dim3(256), 0, stream, W2, W2b, (int)(N_W1 / 4));
    hipLaunchKernelGGL(cvt_bf16, dim3((unsigned)(N_W3 / 4 / 256)), dim3(256), 0, stream, W3, W3b, (int)(N_W3 / 4));
    hipLaunchKernelGGL(ode_reg, dim3(NWG), dim3(TPB_R), 0, stream,
                       ts, y0, W0b, b0, W1b, b1, W2b, b2, W3b, b3,
                       out, hA, hB, gcnt, root);
  } else {
    hipLaunchKernelGGL(ode_stream, dim3(NWG), dim3(TPB_S), 0, stream,
                       ts, y0, W0, b0, W1, b1, W2, b2, W3, b3,
                       out, hA, hB, gcnt, root);
  }
}

// Round 9
// 29779.239 us; speedup vs baseline: 2.4509x; 2.4509x over previous
//
#include <hip/hip_runtime.h>

#define NWG   256
#define TPB_R 1024    // resident kernel: 16 waves, 1 WG/CU (LDS-enforced), 128 VGPR/thread
#define TPB_S 1024    // fallback streaming kernel
#define NSTEP 1000
#define NDATA 2048
#define WIDTH 4096

typedef __attribute__((ext_vector_type(4))) float f32x4;
typedef __attribute__((ext_vector_type(2))) float f32x2;
typedef __attribute__((ext_vector_type(2))) unsigned int u32x2;
typedef __attribute__((ext_vector_type(4))) unsigned int u32x4;
typedef unsigned int uint;

#define SCHED_FENCE() __builtin_amdgcn_sched_barrier(0)

// ---------- scalar helpers ----------

__device__ __forceinline__ float sp_f(float v) {
  // jax.nn.softplus == max(v,0) + log1p(exp(-|v|))
  return fmaxf(v, 0.0f) + log1pf(expf(-fabsf(v)));
}

__device__ __forceinline__ float wred(float v) {
#pragma unroll
  for (int m = 32; m > 0; m >>= 1) v += __shfl_xor(v, m, 64);
  return v;
}

// ---------- waits / barriers ----------

__device__ __forceinline__ void wait_vm0()   { asm volatile("s_waitcnt vmcnt(0)" ::: "memory"); SCHED_FENCE(); }
template<int N>
__device__ __forceinline__ void wait_vmN()   { asm volatile("s_waitcnt vmcnt(%0)" :: "n"(N) : "memory"); SCHED_FENCE(); }
__device__ __forceinline__ void wait_lgkm0() { asm volatile("s_waitcnt lgkmcnt(0)" ::: "memory"); SCHED_FENCE(); }
__device__ __forceinline__ void wgbar()      { __builtin_amdgcn_s_barrier(); SCHED_FENCE(); }

// ---------- L2-bypass (IC-coherent) I/O: sc0 sc1 ----------

__device__ __forceinline__ void st_sc_x1(float* p, float v) {
  asm volatile("global_store_dword %0, %1, off sc0 sc1" :: "v"(p), "v"(v) : "memory");
}
__device__ __forceinline__ void ld_sc_x1_issue(const float* p, float& v) {
  asm volatile("global_load_dword %0, %1, off sc0 sc1" : "=v"(v) : "v"(p) : "memory");
}
__device__ __forceinline__ void ld_sc_x4_issue(const f32x4* p, f32x4& v) {
  asm volatile("global_load_dwordx4 %0, %1, off sc0 sc1" : "=v"(v) : "v"(p) : "memory");
}
__device__ __forceinline__ uint ld_sc_u32(const uint* p) {
  uint v;
  asm volatile("global_load_dword %0, %1, off sc0 sc1\n\ts_waitcnt vmcnt(0)"
               : "=v"(v) : "v"(p) : "memory");
  return v;
}
__device__ __forceinline__ void st_sc_u32(uint* p, uint v) {
  asm volatile("global_store_dword %0, %1, off sc0 sc1" :: "v"(p), "v"(v) : "memory");
}

// ---------- activation staging into LDS ----------

__device__ __forceinline__ void stage4096_1k(const float* src, float* xs, int tid) {
  f32x4 a;
  ld_sc_x4_issue((const f32x4*)src + tid, a);
  wait_vm0();
  ((f32x4*)xs)[tid] = a;
  wait_lgkm0();
  wgbar();
}
__device__ __forceinline__ void stage2048_1k(const float* src, float* xs, int tid) {
  f32x4 a;
  bool act = tid < 512;
  if (act) ld_sc_x4_issue((const f32x4*)src + tid, a);
  wait_vm0();
  if (act) ((f32x4*)xs)[tid] = a;
  wait_lgkm0();
  wgbar();
}

// ---------- flag/aggregator grid barrier (fence-free, monotonic tags) ----------
// Arrive: WG w (w>0) tid0 bypass-stores tag to arrive[w*16] (parallel, no RMW).
// WG0: threads 1..255 each poll one flag; s_barrier; tid0 stores `go`=tag.
// Everyone else polls `go`. All flag ops are sc0sc1 (IC-coherent). Data was
// drained (vmcnt) before the leading wgbar, so IC order guarantees visibility.
__device__ __forceinline__ void gbar(uint* arrive, uint* go, uint tag,
                                     int wg, int tid) {
  wgbar();
  if (wg == 0) {
    if (tid >= 1 && tid < NWG) {
      while (ld_sc_u32(arrive + tid * 16) < tag) __builtin_amdgcn_s_sleep(1);
    }
    wgbar();
    if (tid == 0) st_sc_u32(go, tag);
  } else {
    if (tid == 0) {
      st_sc_u32(arrive + wg * 16, tag);
      while (ld_sc_u32(go) < tag) __builtin_amdgcn_s_sleep(1);
    }
    wgbar();
  }
}

// ---------- fp32 -> bf16 (RNE) weight conversion ----------

__device__ __forceinline__ uint bfr(float f) {
  uint u = __float_as_uint(f);
  return (u + 0x7fffu + ((u >> 16) & 1u)) >> 16;
}

__global__ void cvt_bf16(const float* __restrict__ in, uint* __restrict__ out, int n4) {
  int i = blockIdx.x * 256 + threadIdx.x;
  if (i >= n4) return;
  f32x4 v = ((const f32x4*)in)[i];
  u32x2 o;
  o.x = bfr(v.x) | (bfr(v.y) << 16);
  o.y = bfr(v.z) | (bfr(v.w) << 16);
  ((u32x2*)out)[i] = o;
}

// ---------- bf16 dot macros (named SSA values only, no arrays) ----------
// u32x4 Q = chunk j of a row: covers x[j*512 + lane*8 .. +8)
//   Q.x->(xv0.x,xv0.y) Q.y->(xv0.z,xv0.w) Q.z->(xv1.x,xv1.y) Q.w->(xv1.z,xv1.w)

#define QFMA(Q, x0, x1) do{                                        \
  s0 = fmaf(__uint_as_float((Q).x << 16),          (x0).x, s0);    \
  s0 = fmaf(__uint_as_float((Q).x & 0xffff0000u),  (x0).y, s0);    \
  s0 = fmaf(__uint_as_float((Q).y << 16),          (x0).z, s0);    \
  s0 = fmaf(__uint_as_float((Q).y & 0xffff0000u),  (x0).w, s0);    \
  s0 = fmaf(__uint_as_float((Q).z << 16),          (x1).x, s0);    \
  s0 = fmaf(__uint_as_float((Q).z & 0xffff0000u),  (x1).y, s0);    \
  s0 = fmaf(__uint_as_float((Q).w << 16),          (x1).z, s0);    \
  s0 = fmaf(__uint_as_float((Q).w & 0xffff0000u),  (x1).w, s0);    \
}while(0)

#define CHUNK(j, Q, off) do{                                       \
  f32x4 xv0 = x4[(off) + (j)*128 + 2*lane];                        \
  f32x4 xv1 = x4[(off) + (j)*128 + 2*lane + 1];                    \
  QFMA(Q, xv0, xv1);                                               \
}while(0)

#define CHUNK_L(j) do{                                             \
  u32x4 Q = w1p[(j)*64 + lane];                                    \
  f32x4 xv0 = x4[(j)*128 + 2*lane];                                \
  f32x4 xv1 = x4[(j)*128 + 2*lane + 1];                            \
  QFMA(Q, xv0, xv1);                                               \
}while(0)

// ======================================================================
// HYBRID-RESIDENT kernel (TPB=1024, 16 waves, 1 WG/CU):
//   per-CU weight slice 384 KB = 256 KB in VGPRs (W0+W2+W3, 64 named
//   regs/thread, fits the hard 128-VGPR/thread budget at 16 waves) +
//   128 KB in LDS (W1). Zero weight memory traffic in the step loop.
//   Rounds 6-8 proved TPB=512 cannot get a 256-VGPR budget -> spill.
// ======================================================================

__global__ void __launch_bounds__(TPB_R, 4) ode_res(
    const float* __restrict__ ts, const float* __restrict__ y0,
    const uint* __restrict__ W0b, const float* __restrict__ b0,
    const uint* __restrict__ W1b, const float* __restrict__ b1,
    const uint* __restrict__ W2b, const float* __restrict__ b2,
    const uint* __restrict__ W3b, const float* __restrict__ b3,
    float* __restrict__ out, float* hA, float* hB,
    uint* arrive, uint* go)
{
  __shared__ u32x4 W1lds[16 * 512];   // 128 KB: row w = W1 row (wg*16+w)
  __shared__ float xs[WIDTH];         // 16 KB
  __shared__ float ps[16];
  const int wg = blockIdx.x, tid = threadIdx.x;
  const int wave = tid >> 6, lane = tid & 63;
  const float dt = ts[1] - ts[0];
  const int r  = wg * 16 + wave;        // L0/L1/L2 output row (1 row/wave)
  const int rF = wg * 8 + (wave >> 1);  // LF row (2 waves/row)
  const int hf = wave & 1;
  const f32x4* x4 = (const f32x4*)xs;
  const u32x4* w1p = &W1lds[wave * 512];

  // ---- prologue: W1 slice -> LDS; W0/W2/W3 slices -> named registers ----
  {
    const u32x4* p1 = (const u32x4*)W1b + (size_t)r * 512;
#pragma unroll
    for (int j = 0; j < 8; ++j)
      W1lds[wave * 512 + j * 64 + lane] = p1[j * 64 + lane];
  }
  const u32x4* pA = (const u32x4*)W0b + (size_t)r * 256;                    // W0 row: 256 u32x4
  const u32x4* pC = (const u32x4*)W2b + (size_t)r * 512;                    // W2 row: 512 u32x4
  const u32x4* pD = (const u32x4*)W3b + (size_t)rF * 512 + (size_t)hf * 256; // W3 half-row

  u32x4 A0 = pA[0*64+lane], A1 = pA[1*64+lane], A2 = pA[2*64+lane], A3 = pA[3*64+lane];
  u32x4 C0 = pC[0*64+lane], C1 = pC[1*64+lane], C2 = pC[2*64+lane], C3 = pC[3*64+lane];
  u32x4 C4 = pC[4*64+lane], C5 = pC[5*64+lane], C6 = pC[6*64+lane], C7 = pC[7*64+lane];
  u32x4 D0 = pD[0*64+lane], D1 = pD[1*64+lane], D2 = pD[2*64+lane], D3 = pD[3*64+lane];

  const float bw0 = b0[r], bw1 = b1[r], bw2 = b2[r], bf3 = b3[rF];
  wait_lgkm0();
  wgbar();                              // W1lds ready

  uint tag = 0;
  const float* yin = y0;
  for (int step = 0; step < NSTEP; ++step) {
    float s0;
    // ---- L0: 2048 -> 4096, softplus (W0 in regs) ----
    stage2048_1k(yin, xs, tid);
    s0 = 0.f;
    CHUNK(0, A0, 0); CHUNK(1, A1, 0); CHUNK(2, A2, 0); CHUNK(3, A3, 0);
    s0 = wred(s0);
    if (lane == 0) st_sc_x1(hA + r, sp_f(s0 + bw0));
    wait_vm0();
    gbar(arrive, go, ++tag, wg, tid);

    // ---- L1: 4096 -> 4096, softplus (W1 in LDS) ----
    stage4096_1k(hA, xs, tid);
    s0 = 0.f;
    CHUNK_L(0); CHUNK_L(1); CHUNK_L(2); CHUNK_L(3);
    CHUNK_L(4); CHUNK_L(5); CHUNK_L(6); CHUNK_L(7);
    s0 = wred(s0);
    if (lane == 0) st_sc_x1(hB + r, sp_f(s0 + bw1));
    wait_vm0();
    gbar(arrive, go, ++tag, wg, tid);

    // ---- L2: 4096 -> 4096, softplus (W2 in regs) ----
    stage4096_1k(hB, xs, tid);
    s0 = 0.f;
    CHUNK(0, C0, 0); CHUNK(1, C1, 0); CHUNK(2, C2, 0); CHUNK(3, C3, 0);
    CHUNK(4, C4, 0); CHUNK(5, C5, 0); CHUNK(6, C6, 0); CHUNK(7, C7, 0);
    s0 = wred(s0);
    if (lane == 0) st_sc_x1(hA + r, sp_f(s0 + bw2));
    wait_vm0();
    gbar(arrive, go, ++tag, wg, tid);

    // ---- LF: 4096 -> 2048, y += dt*(W3 h + b3) (W3 in regs, 2-wave split-K) ----
    stage4096_1k(hA, xs, tid);
    float yo;
    ld_sc_x1_issue(yin + rF, yo);       // all lanes same addr; in flight over dot
    s0 = 0.f;
    CHUNK(0, D0, hf * 512); CHUNK(1, D1, hf * 512);
    CHUNK(2, D2, hf * 512); CHUNK(3, D3, hf * 512);
    s0 = wred(s0);
    if (lane == 0) ps[wave] = s0;
    wait_lgkm0();
    wgbar();                            // ps visible
    wait_vm0();                         // yo ready
    float* yout = out + (size_t)step * NDATA;
    if (hf == 0 && lane == 0)
      st_sc_x1(yout + rF, yo + dt * (ps[wave] + ps[wave + 1] + bf3));
    wait_vm0();
    gbar(arrive, go, ++tag, wg, tid);
    yin = yout;                         // y state lives in d_out rows
  }
}

// ======================================================================
// FALLBACK (ws too small for bf16 buffers): round-5 fp32 streaming kernel.
// ======================================================================

__device__ __forceinline__ void issue_row_f32(const float* W, size_t elemidx, int lane, f32x4* wr, int ni) {
  const f32x4* p = (const f32x4*)(W + elemidx) + lane;
  for (int i = 0; i < ni; ++i)
    asm volatile("global_load_dwordx4 %0, %1, off" : "=v"(wr[i]) : "v"(p + i * 64) : "memory");
}

template<int NI>
__device__ __forceinline__ float dot_row_f32(const f32x4* wr, const float* xs, int xoff, int lane) {
  const f32x4* x4 = (const f32x4*)xs + xoff;
  float a = 0.f;
#pragma unroll
  for (int i = 0; i < NI; ++i) {
    f32x4 xv = x4[i * 64 + lane];
    a = fmaf(wr[i].x, xv.x, a); a = fmaf(wr[i].y, xv.y, a);
    a = fmaf(wr[i].z, xv.z, a); a = fmaf(wr[i].w, xv.w, a);
  }
  return a;
}

__global__ void __launch_bounds__(TPB_S, 1) ode_stream(
    const float* __restrict__ ts, const float* __restrict__ y0,
    const float* __restrict__ W0, const float* __restrict__ b0,
    const float* __restrict__ W1, const float* __restrict__ b1,
    const float* __restrict__ W2, const float* __restrict__ b2,
    const float* __restrict__ W3, const float* __restrict__ b3,
    float* __restrict__ out, float* hA, float* hB,
    uint* arrive, uint* go)
{
  __shared__ float xs[WIDTH];
  __shared__ float ps[16];
  const int wg = blockIdx.x, tid = threadIdx.x;
  const int wave = tid >> 6, lane = tid & 63;
  const float dt = ts[1] - ts[0];
  const int rw = wg * 16 + wave;
  const int rF = wg * 8 + (wave >> 1);
  const int hf = wave & 1;

  f32x4 w0r[8], w1r[16], w2r[16], w3r[8];
  issue_row_f32(W0, (size_t)rw * NDATA, lane, w0r, 8);

  uint tag = 0;
  const float* yin = y0;
  for (int step = 0; step < NSTEP; ++step) {
    stage2048_1k(yin, xs, tid);
    float a = wred(dot_row_f32<8>(w0r, xs, 0, lane));
    if (lane == 0) st_sc_x1(hA + rw, sp_f(a + b0[rw]));
    issue_row_f32(W1, (size_t)rw * WIDTH, lane, w1r, 16);
    wait_vmN<16>();
    gbar(arrive, go, ++tag, wg, tid);

    stage4096_1k(hA, xs, tid);
    a = wred(dot_row_f32<16>(w1r, xs, 0, lane));
    if (lane == 0) st_sc_x1(hB + rw, sp_f(a + b1[rw]));
    issue_row_f32(W2, (size_t)rw * WIDTH, lane, w2r, 16);
    wait_vmN<16>();
    gbar(arrive, go, ++tag, wg, tid);

    stage4096_1k(hB, xs, tid);
    a = wred(dot_row_f32<16>(w2r, xs, 0, lane));
    if (lane == 0) st_sc_x1(hA + rw, sp_f(a + b2[rw]));
    issue_row_f32(W3, (size_t)rF * WIDTH + (size_t)hf * 2048, lane, w3r, 8);
    wait_vmN<8>();
    gbar(arrive, go, ++tag, wg, tid);

    stage4096_1k(hA, xs, tid);
    float yo;
    ld_sc_x1_issue(yin + rF, yo);
    a = wred(dot_row_f32<8>(w3r, xs, hf * 512, lane));
    if (lane == 0) ps[wave] = a;
    wait_lgkm0();
    wgbar();
    wait_vm0();
    float* yout = out + (size_t)step * NDATA;
    if (hf == 0 && lane == 0) {
      float tot = ps[wave] + ps[wave + 1];
      st_sc_x1(yout + rF, yo + dt * (tot + b3[rF]));
    }
    issue_row_f32(W0, (size_t)rw * NDATA, lane, w0r, 8);
    wait_vmN<8>();
    gbar(arrive, go, ++tag, wg, tid);
    yin = yout;
  }
}

// ---------- launch ----------

#define WS_HA   0
#define WS_HB   16384
#define WS_CNT  32768
#define WS_WB   65536
static const size_t N_W0 = (size_t)WIDTH * NDATA;   // 8.39M
static const size_t N_W1 = (size_t)WIDTH * WIDTH;   // 16.78M
static const size_t N_W3 = (size_t)NDATA * WIDTH;   // 8.39M

extern "C" void kernel_launch(void* const* d_in, const int* in_sizes, int n_in,
                              void* d_out, int out_size, void* d_ws, size_t ws_size,
                              hipStream_t stream) {
  const float* ts = (const float*)d_in[0];
  const float* y0 = (const float*)d_in[1];
  const float* W0 = (const float*)d_in[2];
  const float* b0 = (const float*)d_in[3];
  const float* W1 = (const float*)d_in[4];
  const float* b1 = (const float*)d_in[5];
  const float* W2 = (const float*)d_in[6];
  const float* b2 = (const float*)d_in[7];
  const float* W3 = (const float*)d_in[8];
  const float* b3 = (const float*)d_in[9];
  float* out = (float*)d_out;

  char* ws = (char*)d_ws;
  float* hA     = (float*)(ws + WS_HA);
  float* hB     = (float*)(ws + WS_HB);
  uint*  arrive = (uint*)(ws + WS_CNT);             // 256 x 64B lines
  uint*  go     = (uint*)(ws + WS_CNT + 16384);

  hipMemsetAsync(ws + WS_CNT, 0, 32768, stream);    // zero arrive + go

  const size_t need = WS_WB + (N_W0 + 2 * N_W1 + N_W3) * 2;  // ~100.7 MB
  if (ws_size >= need) {
    uint* W0b = (uint*)(ws + WS_WB);
    uint* W1b = W0b + N_W0 / 2;
    uint* W2b = W1b + N_W1 / 2;
    uint* W3b = W2b + N_W1 / 2;
    hipLaunchKernelGGL(cvt_bf16, dim3((unsigned)(N_W0 / 4 / 256)), dim3(256), 0, stream, W0, W0b, (int)(N_W0 / 4));
    hipLaunchKernelGGL(cvt_bf16, dim3((unsigned)(N_W1 / 4 / 256)), dim3(256), 0, stream, W1, W1b, (int)(N_W1 / 4));
    hipLaunchKernelGGL(cvt_bf16, dim3((unsigned)(N_W1 / 4 / 256)), dim3(256), 0, stream, W2, W2b, (int)(N_W1 / 4));
    hipLaunchKernelGGL(cvt_bf16, dim3((unsigned)(N_W3 / 4 / 256)), dim3(256), 0, stream, W3, W3b, (int)(N_W3 / 4));
    hipLaunchKernelGGL(ode_res, dim3(NWG), dim3(TPB_R), 0, stream,
                       ts, y0, W0b, b0, W1b, b1, W2b, b2, W3b, b3,
                       out, hA, hB, arrive, go);
  } else {
    hipLaunchKernelGGL(ode_stream, dim3(NWG), dim3(TPB_S), 0, stream,
                       ts, y0, W0, b0, W1, b1, W2, b2, W3, b3,
                       out, hA, hB, arrive, go);
  }
}

// Round 10
// 27272.549 us; speedup vs baseline: 2.6762x; 1.0919x over previous
//
#include <hip/hip_runtime.h>

#define NWG   256
#define TPB_R 256     // resident kernel: 4 waves, 1/SIMD -> ~256-VGPR budget (empirical law)
#define TPB_S 1024    // fallback streaming kernel
#define NSTEP 1000
#define NDATA 2048
#define WIDTH 4096

typedef __attribute__((ext_vector_type(4))) float f32x4;
typedef __attribute__((ext_vector_type(2))) float f32x2;
typedef __attribute__((ext_vector_type(2))) unsigned int u32x2;
typedef __attribute__((ext_vector_type(4))) unsigned int u32x4;
typedef unsigned int uint;

#define SCHED_FENCE() __builtin_amdgcn_sched_barrier(0)

// ---------- scalar helpers ----------

__device__ __forceinline__ float sp_f(float v) {
  // jax.nn.softplus == max(v,0) + log1p(exp(-|v|))
  return fmaxf(v, 0.0f) + log1pf(expf(-fabsf(v)));
}

__device__ __forceinline__ float wred(float v) {
#pragma unroll
  for (int m = 32; m > 0; m >>= 1) v += __shfl_xor(v, m, 64);
  return v;
}

// ---------- waits / barriers ----------

__device__ __forceinline__ void wait_vm0()   { asm volatile("s_waitcnt vmcnt(0)" ::: "memory"); SCHED_FENCE(); }
template<int N>
__device__ __forceinline__ void wait_vmN()   { asm volatile("s_waitcnt vmcnt(%0)" :: "n"(N) : "memory"); SCHED_FENCE(); }
__device__ __forceinline__ void wait_lgkm0() { asm volatile("s_waitcnt lgkmcnt(0)" ::: "memory"); SCHED_FENCE(); }
__device__ __forceinline__ void wgbar()      { __builtin_amdgcn_s_barrier(); SCHED_FENCE(); }

// ---------- L2-bypass (IC-coherent) I/O: sc0 sc1 ----------

__device__ __forceinline__ void st_sc_x1(float* p, float v) {
  asm volatile("global_store_dword %0, %1, off sc0 sc1" :: "v"(p), "v"(v) : "memory");
}
__device__ __forceinline__ void st_sc_x2(float* p, f32x2 v) {
  asm volatile("global_store_dwordx2 %0, %1, off sc0 sc1" :: "v"(p), "v"(v) : "memory");
}
__device__ __forceinline__ void st_sc_x4(float* p, f32x4 v) {
  asm volatile("global_store_dwordx4 %0, %1, off sc0 sc1" :: "v"(p), "v"(v) : "memory");
}
__device__ __forceinline__ void ld_sc_x2_issue(const float* p, f32x2& v) {
  asm volatile("global_load_dwordx2 %0, %1, off sc0 sc1" : "=v"(v) : "v"(p) : "memory");
}
__device__ __forceinline__ void ld_sc_x4_issue(const f32x4* p, f32x4& v) {
  asm volatile("global_load_dwordx4 %0, %1, off sc0 sc1" : "=v"(v) : "v"(p) : "memory");
}
__device__ __forceinline__ void ld_sc_x1_issue(const float* p, float& v) {
  asm volatile("global_load_dword %0, %1, off sc0 sc1" : "=v"(v) : "v"(p) : "memory");
}
__device__ __forceinline__ uint ld_sc_u32(const uint* p) {
  uint v;
  asm volatile("global_load_dword %0, %1, off sc0 sc1\n\ts_waitcnt vmcnt(0)"
               : "=v"(v) : "v"(p) : "memory");
  return v;
}
__device__ __forceinline__ void st_sc_u32(uint* p, uint v) {
  asm volatile("global_store_dword %0, %1, off sc0 sc1" :: "v"(p), "v"(v) : "memory");
}

// plain cached load (L2-served), issue-only
__device__ __forceinline__ void ld_g(const u32x4* p, u32x4& v) {
  asm volatile("global_load_dwordx4 %0, %1, off" : "=v"(v) : "v"(p) : "memory");
}

// ---------- activation staging into LDS (TPB=256) ----------

__device__ __forceinline__ void stage4096_256(const float* src, float* xs, int tid) {
  f32x4 a, b, c, d;
  ld_sc_x4_issue((const f32x4*)src + tid,       a);
  ld_sc_x4_issue((const f32x4*)src + tid + 256, b);
  ld_sc_x4_issue((const f32x4*)src + tid + 512, c);
  ld_sc_x4_issue((const f32x4*)src + tid + 768, d);
  wait_vm0();
  ((f32x4*)xs)[tid]       = a;
  ((f32x4*)xs)[tid + 256] = b;
  ((f32x4*)xs)[tid + 512] = c;
  ((f32x4*)xs)[tid + 768] = d;
  wait_lgkm0();
  wgbar();
}
__device__ __forceinline__ void stage2048_256(const float* src, float* xs, int tid) {
  f32x4 a, b;
  ld_sc_x4_issue((const f32x4*)src + tid,       a);
  ld_sc_x4_issue((const f32x4*)src + tid + 256, b);
  wait_vm0();
  ((f32x4*)xs)[tid]       = a;
  ((f32x4*)xs)[tid + 256] = b;
  wait_lgkm0();
  wgbar();
}

// ---------- flag/aggregator grid barrier (fence-free, monotonic tags) ----------

__device__ __forceinline__ void gbar(uint* arrive, uint* go, uint tag,
                                     int wg, int tid) {
  wgbar();
  if (wg == 0) {
    if (tid >= 1 && tid < NWG) {
      while (ld_sc_u32(arrive + tid * 16) < tag) __builtin_amdgcn_s_sleep(1);
    }
    wgbar();
    if (tid == 0) st_sc_u32(go, tag);
  } else {
    if (tid == 0) {
      st_sc_u32(arrive + wg * 16, tag);
      while (ld_sc_u32(go) < tag) __builtin_amdgcn_s_sleep(1);
    }
    wgbar();
  }
}

// ---------- fp32 -> permuted bf16 u32x4 chunks ----------
// Chunk c = j*64+lane of row r covers x[j*512+lane*4 .. +4) (lo) and
// x[j*512+256+lane*4 .. +4) (hi) -> dot reads x4[j*128+lane], x4[j*128+64+lane]
// (both stride-16B across lanes: LDS-conflict-free).

__device__ __forceinline__ uint bfr(float f) {
  uint u = __float_as_uint(f);
  return (u + 0x7fffu + ((u >> 16) & 1u)) >> 16;
}

__global__ void cvt_perm(const float* __restrict__ in, u32x4* __restrict__ out,
                         int rows, int K) {
  int idx = blockIdx.x * 256 + threadIdx.x;
  int cpr = K >> 3;                      // u32x4 chunks per row
  if (idx >= rows * cpr) return;
  int row = idx / cpr, c = idx - row * cpr;
  int j = c >> 6, lane = c & 63;
  const f32x4* p = (const f32x4*)(in + (size_t)row * K + j * 512 + lane * 4);
  f32x4 lo = p[0];
  f32x4 hi = p[64];                      // +256 elements
  u32x4 o;
  o.x = bfr(lo.x) | (bfr(lo.y) << 16);
  o.y = bfr(lo.z) | (bfr(lo.w) << 16);
  o.z = bfr(hi.x) | (bfr(hi.y) << 16);
  o.w = bfr(hi.z) | (bfr(hi.w) << 16);
  out[idx] = o;
}

// ---------- dot of one permuted chunk against LDS x ----------

#define DC(Q, j, s) do{                                              \
  f32x4 xa = x4[(j)*128 + lane];                                     \
  f32x4 xb = x4[(j)*128 + 64 + lane];                                \
  s = fmaf(__uint_as_float((Q).x << 16),         xa.x, s);           \
  s = fmaf(__uint_as_float((Q).x & 0xffff0000u), xa.y, s);           \
  s = fmaf(__uint_as_float((Q).y << 16),         xa.z, s);           \
  s = fmaf(__uint_as_float((Q).y & 0xffff0000u), xa.w, s);           \
  s = fmaf(__uint_as_float((Q).z << 16),         xb.x, s);           \
  s = fmaf(__uint_as_float((Q).z & 0xffff0000u), xb.y, s);           \
  s = fmaf(__uint_as_float((Q).w << 16),         xb.z, s);           \
  s = fmaf(__uint_as_float((Q).w & 0xffff0000u), xb.w, s);           \
}while(0)

#define DL(row, j, s) do{ u32x4 Q = W1lds[(row)*512 + (j)*64 + lane]; DC(Q, j, s); }while(0)

#define SREG(x) __int_as_float(__builtin_amdgcn_readfirstlane(__float_as_int(x)))

// ======================================================================
// RESIDENT kernel, TPB=256 (the only TPB whose VGPR budget is ~256):
//   LDS  : W1 (128 KB)                      [proven round 9]
//   VGPRs: W2 (32 u32x4 = 128) + W3 (16 u32x4 = 64) = 192 named regs
//   L2   : W0 streamed per step (2 MB/XCD -> L2-resident, never invalidated)
// Weight layout: permuted u32x4 chunks -> stride-16B x reads, conflict-free.
// ======================================================================

__global__ void __launch_bounds__(TPB_R, 1) ode_res(
    const float* __restrict__ ts, const float* __restrict__ y0,
    const u32x4* __restrict__ W0p, const float* __restrict__ b0,
    const u32x4* __restrict__ W1p, const float* __restrict__ b1,
    const u32x4* __restrict__ W2p, const float* __restrict__ b2,
    const u32x4* __restrict__ W3p, const float* __restrict__ b3,
    float* __restrict__ out, float* hA, float* hB,
    uint* arrive, uint* go)
{
  __shared__ u32x4 W1lds[16 * 512];   // 128 KB: [row within WG][chunk]
  __shared__ float xs[WIDTH];         // 16 KB
  const int wg = blockIdx.x, tid = threadIdx.x;
  const int wave = tid >> 6, lane = tid & 63;
  const float dt = ts[1] - ts[0];
  const int rw = wg * 16 + wave * 4;   // wide layers: 4 rows/wave
  const int rf = wg * 8 + wave * 2;    // final layer: 2 rows/wave
  const f32x4* x4 = (const f32x4*)xs;

  // ---- prologue: W1 -> LDS (linear copy of this WG's 16 rows) ----
#pragma unroll
  for (int k = 0; k < 32; ++k)
    W1lds[k * 256 + tid] = W1p[(size_t)wg * 8192 + k * 256 + tid];

  // ---- W2 resident: 32 named u32x4 (128 VGPRs) ----
#define L2W(r,j) W2p[(size_t)(rw+(r))*512 + (j)*64 + lane]
  u32x4 C00=L2W(0,0),C01=L2W(0,1),C02=L2W(0,2),C03=L2W(0,3),C04=L2W(0,4),C05=L2W(0,5),C06=L2W(0,6),C07=L2W(0,7);
  u32x4 C10=L2W(1,0),C11=L2W(1,1),C12=L2W(1,2),C13=L2W(1,3),C14=L2W(1,4),C15=L2W(1,5),C16=L2W(1,6),C17=L2W(1,7);
  u32x4 C20=L2W(2,0),C21=L2W(2,1),C22=L2W(2,2),C23=L2W(2,3),C24=L2W(2,4),C25=L2W(2,5),C26=L2W(2,6),C27=L2W(2,7);
  u32x4 C30=L2W(3,0),C31=L2W(3,1),C32=L2W(3,2),C33=L2W(3,3),C34=L2W(3,4),C35=L2W(3,5),C36=L2W(3,6),C37=L2W(3,7);
  // ---- W3 resident: 16 named u32x4 (64 VGPRs) ----
#define L3W(r,j) W3p[(size_t)(rf+(r))*512 + (j)*64 + lane]
  u32x4 D00=L3W(0,0),D01=L3W(0,1),D02=L3W(0,2),D03=L3W(0,3),D04=L3W(0,4),D05=L3W(0,5),D06=L3W(0,6),D07=L3W(0,7);
  u32x4 D10=L3W(1,0),D11=L3W(1,1),D12=L3W(1,2),D13=L3W(1,3),D14=L3W(1,4),D15=L3W(1,5),D16=L3W(1,6),D17=L3W(1,7);

  // ---- biases in SGPRs (wave-uniform) ----
  const float b00=SREG(b0[rw]), b01=SREG(b0[rw+1]), b02=SREG(b0[rw+2]), b03=SREG(b0[rw+3]);
  const float b10=SREG(b1[rw]), b11=SREG(b1[rw+1]), b12=SREG(b1[rw+2]), b13=SREG(b1[rw+3]);
  const float b20=SREG(b2[rw]), b21=SREG(b2[rw+1]), b22=SREG(b2[rw+2]), b23=SREG(b2[rw+3]);
  const float b30=SREG(b3[rf]), b31=SREG(b3[rf+1]);

  wait_vm0(); wait_lgkm0();
  wgbar();                              // W1lds + residents ready

  // W0 stream: 4 rows/wave, 4 chunks/row, pipelined with counted vmcnt.
  const u32x4* w0base = W0p + (size_t)rw * 256 + lane;
#define ISSW0(r, Qa, Qb, Qc, Qd) do{ const u32x4* p_ = w0base + (size_t)(r)*256; \
  ld_g(p_, Qa); ld_g(p_+64, Qb); ld_g(p_+128, Qc); ld_g(p_+192, Qd); }while(0)

  u32x4 E0a,E0b,E0c,E0d, E1a,E1b,E1c,E1d, E2a,E2b,E2c,E2d, E3a,E3b,E3c,E3d;
  ISSW0(0, E0a,E0b,E0c,E0d);            // prologue prefetch (lands under stage)

  uint tag = 0;
  const float* yin = y0;
  for (int step = 0; step < NSTEP; ++step) {
    float s0, s1, s2, s3;
    // ---- L0: 2048 -> 4096, softplus (W0 L2-streamed, pipelined) ----
    stage2048_256(yin, xs, tid);        // wait_vm0 inside also lands E0
    ISSW0(1, E1a,E1b,E1c,E1d);
    s0 = 0.f; DC(E0a,0,s0); DC(E0b,1,s0); DC(E0c,2,s0); DC(E0d,3,s0);
    ISSW0(2, E2a,E2b,E2c,E2d);
    wait_vmN<4>();                      // E1 landed, E2 in flight
    s1 = 0.f; DC(E1a,0,s1); DC(E1b,1,s1); DC(E1c,2,s1); DC(E1d,3,s1);
    ISSW0(3, E3a,E3b,E3c,E3d);
    wait_vmN<4>();                      // E2 landed, E3 in flight
    s2 = 0.f; DC(E2a,0,s2); DC(E2b,1,s2); DC(E2c,2,s2); DC(E2d,3,s2);
    wait_vm0();                         // E3 landed
    s3 = 0.f; DC(E3a,0,s3); DC(E3b,1,s3); DC(E3c,2,s3); DC(E3d,3,s3);
    s0 = wred(s0); s1 = wred(s1); s2 = wred(s2); s3 = wred(s3);
    if (lane == 0) {
      f32x4 v; v.x = sp_f(s0+b00); v.y = sp_f(s1+b01); v.z = sp_f(s2+b02); v.w = sp_f(s3+b03);
      st_sc_x4(hA + rw, v);
    }
    wait_vm0();
    gbar(arrive, go, ++tag, wg, tid);

    // ---- L1: 4096 -> 4096, softplus (W1 in LDS) ----
    stage4096_256(hA, xs, tid);
    {
      const int r0 = wave * 4;
      s0=0.f; DL(r0+0,0,s0); DL(r0+0,1,s0); DL(r0+0,2,s0); DL(r0+0,3,s0);
              DL(r0+0,4,s0); DL(r0+0,5,s0); DL(r0+0,6,s0); DL(r0+0,7,s0);
      s1=0.f; DL(r0+1,0,s1); DL(r0+1,1,s1); DL(r0+1,2,s1); DL(r0+1,3,s1);
              DL(r0+1,4,s1); DL(r0+1,5,s1); DL(r0+1,6,s1); DL(r0+1,7,s1);
      s2=0.f; DL(r0+2,0,s2); DL(r0+2,1,s2); DL(r0+2,2,s2); DL(r0+2,3,s2);
              DL(r0+2,4,s2); DL(r0+2,5,s2); DL(r0+2,6,s2); DL(r0+2,7,s2);
      s3=0.f; DL(r0+3,0,s3); DL(r0+3,1,s3); DL(r0+3,2,s3); DL(r0+3,3,s3);
              DL(r0+3,4,s3); DL(r0+3,5,s3); DL(r0+3,6,s3); DL(r0+3,7,s3);
    }
    s0 = wred(s0); s1 = wred(s1); s2 = wred(s2); s3 = wred(s3);
    if (lane == 0) {
      f32x4 v; v.x = sp_f(s0+b10); v.y = sp_f(s1+b11); v.z = sp_f(s2+b12); v.w = sp_f(s3+b13);
      st_sc_x4(hB + rw, v);
    }
    wait_vm0();
    gbar(arrive, go, ++tag, wg, tid);

    // ---- L2: 4096 -> 4096, softplus (W2 in regs) ----
    stage4096_256(hB, xs, tid);
    s0=0.f; DC(C00,0,s0); DC(C01,1,s0); DC(C02,2,s0); DC(C03,3,s0);
            DC(C04,4,s0); DC(C05,5,s0); DC(C06,6,s0); DC(C07,7,s0);
    s1=0.f; DC(C10,0,s1); DC(C11,1,s1); DC(C12,2,s1); DC(C13,3,s1);
            DC(C14,4,s1); DC(C15,5,s1); DC(C16,6,s1); DC(C17,7,s1);
    s2=0.f; DC(C20,0,s2); DC(C21,1,s2); DC(C22,2,s2); DC(C23,3,s2);
            DC(C24,4,s2); DC(C25,5,s2); DC(C26,6,s2); DC(C27,7,s2);
    s3=0.f; DC(C30,0,s3); DC(C31,1,s3); DC(C32,2,s3); DC(C33,3,s3);
            DC(C34,4,s3); DC(C35,5,s3); DC(C36,6,s3); DC(C37,7,s3);
    s0 = wred(s0); s1 = wred(s1); s2 = wred(s2); s3 = wred(s3);
    if (lane == 0) {
      f32x4 v; v.x = sp_f(s0+b20); v.y = sp_f(s1+b21); v.z = sp_f(s2+b22); v.w = sp_f(s3+b23);
      st_sc_x4(hA + rw, v);
    }
    wait_vm0();
    gbar(arrive, go, ++tag, wg, tid);

    // ---- LF: 4096 -> 2048, y += dt*(W3 h + b3) (W3 in regs) ----
    stage4096_256(hA, xs, tid);
    f32x2 yo;
    ld_sc_x2_issue(yin + rf, yo);       // in flight during the dots
    s0=0.f; DC(D00,0,s0); DC(D01,1,s0); DC(D02,2,s0); DC(D03,3,s0);
            DC(D04,4,s0); DC(D05,5,s0); DC(D06,6,s0); DC(D07,7,s0);
    s1=0.f; DC(D10,0,s1); DC(D11,1,s1); DC(D12,2,s1); DC(D13,3,s1);
            DC(D14,4,s1); DC(D15,5,s1); DC(D16,6,s1); DC(D17,7,s1);
    s0 = wred(s0); s1 = wred(s1);
    wait_vm0();                         // yo ready
    float* yout = out + (size_t)step * NDATA;
    if (lane == 0) {
      f32x2 v; v.x = yo.x + dt * (s0 + b30); v.y = yo.y + dt * (s1 + b31);
      st_sc_x2(yout + rf, v);
    }
    ISSW0(0, E0a,E0b,E0c,E0d);          // next step's W0 row 0 (L2-hit)
    wait_vmN<4>();                      // drain y store; keep E0 in flight
    gbar(arrive, go, ++tag, wg, tid);
    yin = yout;                         // y state lives in d_out rows
  }
}

// ======================================================================
// FALLBACK (ws too small): round-5-style fp32 streaming kernel, TPB=1024.
// ======================================================================

__device__ __forceinline__ void stage4096_1k(const float* src, float* xs, int tid) {
  f32x4 a;
  ld_sc_x4_issue((const f32x4*)src + tid, a);
  wait_vm0();
  ((f32x4*)xs)[tid] = a;
  wait_lgkm0();
  wgbar();
}
__device__ __forceinline__ void stage2048_1k(const float* src, float* xs, int tid) {
  f32x4 a;
  bool act = tid < 512;
  if (act) ld_sc_x4_issue((const f32x4*)src + tid, a);
  wait_vm0();
  if (act) ((f32x4*)xs)[tid] = a;
  wait_lgkm0();
  wgbar();
}

__device__ __forceinline__ void issue_row_f32(const float* W, size_t elemidx, int lane, f32x4* wr, int ni) {
  const f32x4* p = (const f32x4*)(W + elemidx) + lane;
  for (int i = 0; i < ni; ++i)
    asm volatile("global_load_dwordx4 %0, %1, off" : "=v"(wr[i]) : "v"(p + i * 64) : "memory");
}

template<int NI>
__device__ __forceinline__ float dot_row_f32(const f32x4* wr, const float* xs, int xoff, int lane) {
  const f32x4* x4 = (const f32x4*)xs + xoff;
  float a = 0.f;
#pragma unroll
  for (int i = 0; i < NI; ++i) {
    f32x4 xv = x4[i * 64 + lane];
    a = fmaf(wr[i].x, xv.x, a); a = fmaf(wr[i].y, xv.y, a);
    a = fmaf(wr[i].z, xv.z, a); a = fmaf(wr[i].w, xv.w, a);
  }
  return a;
}

__global__ void __launch_bounds__(TPB_S, 1) ode_stream(
    const float* __restrict__ ts, const float* __restrict__ y0,
    const float* __restrict__ W0, const float* __restrict__ b0,
    const float* __restrict__ W1, const float* __restrict__ b1,
    const float* __restrict__ W2, const float* __restrict__ b2,
    const float* __restrict__ W3, const float* __restrict__ b3,
    float* __restrict__ out, float* hA, float* hB,
    uint* arrive, uint* go)
{
  __shared__ float xs[WIDTH];
  __shared__ float ps[16];
  const int wg = blockIdx.x, tid = threadIdx.x;
  const int wave = tid >> 6, lane = tid & 63;
  const float dt = ts[1] - ts[0];
  const int rw = wg * 16 + wave;
  const int rF = wg * 8 + (wave >> 1);
  const int hf = wave & 1;

  f32x4 w0r[8], w1r[16], w2r[16], w3r[8];
  issue_row_f32(W0, (size_t)rw * NDATA, lane, w0r, 8);

  uint tag = 0;
  const float* yin = y0;
  for (int step = 0; step < NSTEP; ++step) {
    stage2048_1k(yin, xs, tid);
    float a = wred(dot_row_f32<8>(w0r, xs, 0, lane));
    if (lane == 0) st_sc_x1(hA + rw, sp_f(a + b0[rw]));
    issue_row_f32(W1, (size_t)rw * WIDTH, lane, w1r, 16);
    wait_vmN<16>();
    gbar(arrive, go, ++tag, wg, tid);

    stage4096_1k(hA, xs, tid);
    a = wred(dot_row_f32<16>(w1r, xs, 0, lane));
    if (lane == 0) st_sc_x1(hB + rw, sp_f(a + b1[rw]));
    issue_row_f32(W2, (size_t)rw * WIDTH, lane, w2r, 16);
    wait_vmN<16>();
    gbar(arrive, go, ++tag, wg, tid);

    stage4096_1k(hB, xs, tid);
    a = wred(dot_row_f32<16>(w2r, xs, 0, lane));
    if (lane == 0) st_sc_x1(hA + rw, sp_f(a + b2[rw]));
    issue_row_f32(W3, (size_t)rF * WIDTH + (size_t)hf * 2048, lane, w3r, 8);
    wait_vmN<8>();
    gbar(arrive, go, ++tag, wg, tid);

    stage4096_1k(hA, xs, tid);
    float yo;
    ld_sc_x1_issue(yin + rF, yo);
    a = wred(dot_row_f32<8>(w3r, xs, hf * 512, lane));
    if (lane == 0) ps[wave] = a;
    wait_lgkm0();
    wgbar();
    wait_vm0();
    float* yout = out + (size_t)step * NDATA;
    if (hf == 0 && lane == 0) {
      float tot = ps[wave] + ps[wave + 1];
      st_sc_x1(yout + rF, yo + dt * (tot + b3[rF]));
    }
    issue_row_f32(W0, (size_t)rw * NDATA, lane, w0r, 8);
    wait_vmN<8>();
    gbar(arrive, go, ++tag, wg, tid);
    yin = yout;
  }
}

// ---------- launch ----------

#define WS_HA   0
#define WS_HB   16384
#define WS_CNT  32768
#define WS_WB   65536
static const size_t N_W0 = (size_t)WIDTH * NDATA;   // 8.39M elems
static const size_t N_W1 = (size_t)WIDTH * WIDTH;   // 16.78M
static const size_t N_W3 = (size_t)NDATA * WIDTH;   // 8.39M

extern "C" void kernel_launch(void* const* d_in, const int* in_sizes, int n_in,
                              void* d_out, int out_size, void* d_ws, size_t ws_size,
                              hipStream_t stream) {
  const float* ts = (const float*)d_in[0];
  const float* y0 = (const float*)d_in[1];
  const float* W0 = (const float*)d_in[2];
  const float* b0 = (const float*)d_in[3];
  const float* W1 = (const float*)d_in[4];
  const float* b1 = (const float*)d_in[5];
  const float* W2 = (const float*)d_in[6];
  const float* b2 = (const float*)d_in[7];
  const float* W3 = (const float*)d_in[8];
  const float* b3 = (const float*)d_in[9];
  float* out = (float*)d_out;

  char* ws = (char*)d_ws;
  float* hA     = (float*)(ws + WS_HA);
  float* hB     = (float*)(ws + WS_HB);
  uint*  arrive = (uint*)(ws + WS_CNT);             // 256 x 64B lines
  uint*  go     = (uint*)(ws + WS_CNT + 16384);

  hipMemsetAsync(ws + WS_CNT, 0, 32768, stream);    // zero arrive + go

  const size_t need = WS_WB + (N_W0 + 2 * N_W1 + N_W3) * 2;  // ~100.7 MB
  if (ws_size >= need) {
    u32x4* W0p = (u32x4*)(ws + WS_WB);               // N_W0/8 chunks
    u32x4* W1p = W0p + N_W0 / 8;
    u32x4* W2p = W1p + N_W1 / 8;
    u32x4* W3p = W2p + N_W1 / 8;
    hipLaunchKernelGGL(cvt_perm, dim3((unsigned)(N_W0 / 8 / 256)), dim3(256), 0, stream, W0, W0p, WIDTH, NDATA);
    hipLaunchKernelGGL(cvt_perm, dim3((unsigned)(N_W1 / 8 / 256)), dim3(256), 0, stream, W1, W1p, WIDTH, WIDTH);
    hipLaunchKernelGGL(cvt_perm, dim3((unsigned)(N_W1 / 8 / 256)), dim3(256), 0, stream, W2, W2p, WIDTH, WIDTH);
    hipLaunchKernelGGL(cvt_perm, dim3((unsigned)(N_W3 / 8 / 256)), dim3(256), 0, stream, W3, W3p, NDATA, WIDTH);
    hipLaunchKernelGGL(ode_res, dim3(NWG), dim3(TPB_R), 0, stream,
                       ts, y0, W0p, b0, W1p, b1, W2p, b2, W3p, b3,
                       out, hA, hB, arrive, go);
  } else {
    hipLaunchKernelGGL(ode_stream, dim3(NWG), dim3(TPB_S), 0, stream,
                       ts, y0, W0, b0, W1, b1, W2, b2, W3, b3,
                       out, hA, hB, arrive, go);
  }
}